// Round 3
// baseline (215.270 us; speedup 1.0000x reference)
//
#include <hip/hip_runtime.h>

#define EDIM 300
#define NB   128
#define NQ   16
#define ND   1024
#define NK   11
#define BLOCK 128
#define MDOC  4
#define TDOCS 256                 // docs per block
#define BLOCKS_PER_B 4            // 1024 / 256
#define NPANEL 10                 // 9 full 32-float panels + one 12-float remainder
#define PPITCH 36                 // panel row pitch in floats (32 + 4 pad)
#define SIMP 260                  // sim_t row pitch (256 + 4 pad)

// R11: fix R10's overlap failure. R10 post-mortem: __syncthreads() emits
// s_waitcnt vmcnt(0) before s_barrier (the m97 barrier-drain), so the panel
// p+2 gathers issued right before the barrier were DRAINED at the barrier --
// latency still fully exposed, just moved. Fix: lgkm-only barrier in the hot
// loop (8-phase template pattern): my LDS ops complete (lgkmcnt(0)) but the
// 16 global_load_dwordx4 stay in flight across the barrier + compute phase;
// their vmcnt wait lands at the next PF_WRITE, ~2400 VALU cycles later.
#define BARRIER_LGKM() do { \
    asm volatile("s_waitcnt lgkmcnt(0)" ::: "memory"); \
    __builtin_amdgcn_s_barrier(); \
    asm volatile("" ::: "memory"); } while (0)

#define PF_L(j)  pf##j = *(const float4*)(rp##j + pp * 32)
#define PF_LOAD(p) do { const int pp = (p); if (pp < 9 || s < 3) { \
    PF_L(0);  PF_L(1);  PF_L(2);  PF_L(3);  PF_L(4);  PF_L(5);  PF_L(6);  PF_L(7); \
    PF_L(8);  PF_L(9);  PF_L(10); PF_L(11); PF_L(12); PF_L(13); PF_L(14); PF_L(15); } } while (0)

#define PF_S(j)  *(float4*)&panel[(r0 + 16 * (j)) * PPITCH + s * 4] = pf##j
#define PF_WRITE(p) do { if ((p) < 9 || s < 3) { \
    PF_S(0);  PF_S(1);  PF_S(2);  PF_S(3);  PF_S(4);  PF_S(5);  PF_S(6);  PF_S(7); \
    PF_S(8);  PF_S(9);  PF_S(10); PF_S(11); PF_S(12); PF_S(13); PF_S(14); PF_S(15); } } while (0)

__global__ __launch_bounds__(BLOCK, 1) void knrm_main(
    const int*   __restrict__ dtoks,
    const int*   __restrict__ qtoks,
    const float* __restrict__ emb,
    const float* __restrict__ mus,
    const float* __restrict__ sigmas,
    float*       __restrict__ part) {
    __shared__ __align__(16) float qn_s[NQ * EDIM];      // 19.2 KB
    __shared__ __align__(16) float panel[TDOCS * PPITCH];// 36.9 KB
    __shared__ int   dtok_s[TDOCS];                      // 1 KB
    __shared__ float rs_s[NQ];
    __shared__ __align__(16) float sim_t[NQ * SIMP];     // 16.6 KB
    __shared__ float red_s[NK * NQ * 8];                 // 5.6 KB
    // total ~77.6 KB -> 2 blocks/CU

    const int blk   = blockIdx.x;
    const int b     = blk >> 2;
    const int dbase = (blk & 3) * TDOCS;
    const int tid   = threadIdx.x;
    const int lane  = tid & 63;
    const int w     = tid >> 6;          // q-half (wave-uniform)

    // ---- doc-token tile + raw q rows (coalesced, float4-vectorized) ----
    for (int i = tid; i < TDOCS; i += BLOCK) dtok_s[i] = dtoks[b * ND + dbase + i];
    for (int i = tid; i < NQ * (EDIM / 4); i += BLOCK) {   // 300%4==0
        int q = i / (EDIM / 4), e4 = i - q * (EDIM / 4);
        ((float4*)qn_s)[i] =
            *(const float4*)(emb + (size_t)qtoks[b * NQ + q] * EDIM + e4 * 4);
    }
    __syncthreads();                     // dtok_s + raw qn_s visible

    const int s  = tid & 7;              // 128B slice index within a panel row
    const int r0 = tid >> 3;             // 0..15

    // hoisted per-thread row base pointers (rows fixed across panels)
    const float* rp0  = emb + (size_t)dtok_s[r0 +   0] * EDIM + s * 4;
    const float* rp1  = emb + (size_t)dtok_s[r0 +  16] * EDIM + s * 4;
    const float* rp2  = emb + (size_t)dtok_s[r0 +  32] * EDIM + s * 4;
    const float* rp3  = emb + (size_t)dtok_s[r0 +  48] * EDIM + s * 4;
    const float* rp4  = emb + (size_t)dtok_s[r0 +  64] * EDIM + s * 4;
    const float* rp5  = emb + (size_t)dtok_s[r0 +  80] * EDIM + s * 4;
    const float* rp6  = emb + (size_t)dtok_s[r0 +  96] * EDIM + s * 4;
    const float* rp7  = emb + (size_t)dtok_s[r0 + 112] * EDIM + s * 4;
    const float* rp8  = emb + (size_t)dtok_s[r0 + 128] * EDIM + s * 4;
    const float* rp9  = emb + (size_t)dtok_s[r0 + 144] * EDIM + s * 4;
    const float* rp10 = emb + (size_t)dtok_s[r0 + 160] * EDIM + s * 4;
    const float* rp11 = emb + (size_t)dtok_s[r0 + 176] * EDIM + s * 4;
    const float* rp12 = emb + (size_t)dtok_s[r0 + 192] * EDIM + s * 4;
    const float* rp13 = emb + (size_t)dtok_s[r0 + 208] * EDIM + s * 4;
    const float* rp14 = emb + (size_t)dtok_s[r0 + 224] * EDIM + s * 4;
    const float* rp15 = emb + (size_t)dtok_s[r0 + 240] * EDIM + s * 4;

    float4 pf0, pf1, pf2, pf3, pf4, pf5, pf6, pf7,
           pf8, pf9, pf10, pf11, pf12, pf13, pf14, pf15;   // 64 named VGPRs

    PF_LOAD(0);                          // hide panel-0 gather under q-norm phase
    {   // q norms
        int q = tid >> 3, j = tid & 7;
        float ss = 0.f;
        for (int e = j; e < EDIM; e += 8) { float v = qn_s[q * EDIM + e]; ss += v * v; }
        ss += __shfl_xor(ss, 1, 64);
        ss += __shfl_xor(ss, 2, 64);
        ss += __shfl_xor(ss, 4, 64);
        if (j == 0) rs_s[q] = 1.0f / (sqrtf(ss) + 1e-9f);
    }
    __syncthreads();
    for (int i = tid; i < NQ * (EDIM / 4); i += BLOCK) {
        float4 v = ((float4*)qn_s)[i];
        float r = rs_s[i / (EDIM / 4)];
        v.x *= r; v.y *= r; v.z *= r; v.w *= r;
        ((float4*)qn_s)[i] = v;
    }
    PF_WRITE(0);                         // panel 0 -> LDS (vmcnt wait lands here)
    PF_LOAD(1);                          // panel 1 issued; stays in flight
    BARRIER_LGKM();                      // panel 0 + scaled qn_s visible; NO vmcnt drain

    float sims[MDOC][8];
#pragma unroll
    for (int m = 0; m < MDOC; ++m)
#pragma unroll
        for (int qq = 0; qq < 8; ++qq) sims[m][qq] = 0.f;
    float ssq[MDOC] = {0.f, 0.f, 0.f, 0.f};

    for (int p = 0; p < NPANEL; ++p) {
        // ---- compute on panel p (loads for p+1 in flight across this) ----
        const int cmax = (p == 9) ? 3 : 8;
        for (int cc = 0; cc < cmax; ++cc) {
            float4 dv[MDOC];
#pragma unroll
            for (int m = 0; m < MDOC; ++m)
                dv[m] = *(const float4*)&panel[(lane + 64 * m) * PPITCH + cc * 4];
#pragma unroll
            for (int m = 0; m < MDOC; ++m)
                ssq[m] += dv[m].x*dv[m].x + dv[m].y*dv[m].y + dv[m].z*dv[m].z + dv[m].w*dv[m].w;
            const float* qb = qn_s + (size_t)w * 8 * EDIM + (p * 8 + cc) * 4;
#pragma unroll
            for (int qq = 0; qq < 8; ++qq) {
                float4 qv = *(const float4*)(qb + qq * EDIM);   // LDS broadcast
#pragma unroll
                for (int m = 0; m < MDOC; ++m) {
                    sims[m][qq] += qv.x*dv[m].x + qv.y*dv[m].y + qv.z*dv[m].z + qv.w*dv[m].w;
                }
            }
        }
        BARRIER_LGKM();                  // panel p fully consumed; loads still in flight
        if (p < 9) {
            PF_WRITE(p + 1);             // vmcnt wait lands here (loads had full compute to land)
            if (p < 8) PF_LOAD(p + 2);   // issue next gather; stays in flight
            BARRIER_LGKM();              // panel p+1 ready; NO vmcnt drain
        }
    }

    // ---- normalize + write sim_t (pad docs: tok0 -> zero row -> sim 0) ----
#pragma unroll
    for (int m = 0; m < MDOC; ++m) {
        float rn = 1.0f / (sqrtf(ssq[m]) + 1e-9f);
#pragma unroll
        for (int qq = 0; qq < 8; ++qq)
            sim_t[(w * 8 + qq) * SIMP + lane + 64 * m] = sims[m][qq] * rn;
    }
    __syncthreads();

    // ---- RBF bank: thread = (q = tid&15, slice sl of 8 x 32 docs) ----
    {
        const int q = tid & 15;
        const int sl = tid >> 4;
        float mu[NK], cc2[NK], acc[NK];
#pragma unroll
        for (int k = 0; k < NK; ++k) {
            mu[k] = mus[k];
            float sg = sigmas[k];
            cc2[k] = -0.5f / (sg * sg);
            acc[k] = 0.f;
        }
        const float* row = sim_t + q * SIMP + sl * 32;
#pragma unroll
        for (int i = 0; i < 8; ++i) {
            float4 s4 = *(const float4*)(row + i * 4);
#pragma unroll
            for (int k = 0; k < NK; ++k) {
                float e0 = s4.x - mu[k], e1 = s4.y - mu[k];
                float e2 = s4.z - mu[k], e3 = s4.w - mu[k];
                acc[k] += __expf(cc2[k]*e0*e0) + __expf(cc2[k]*e1*e1)
                        + __expf(cc2[k]*e2*e2) + __expf(cc2[k]*e3*e3);
            }
        }
#pragma unroll
        for (int k = 0; k < NK; ++k) red_s[(k * NQ + q) * 8 + sl] = acc[k];
    }
    __syncthreads();

    // NK*NQ = 176 > BLOCK = 128: stride the write (R3 bug class).
    for (int t = tid; t < NK * NQ; t += BLOCK) {
        float r = 0.f;
#pragma unroll
        for (int j = 0; j < 8; ++j) r += red_s[t * 8 + j];
        part[blk * (NK * NQ) + t] = r;
    }
}

// ---------------- Kernel 2: sum partials, masked log-sum over q, FC ----------------
__global__ void knrm_final(const float* __restrict__ part,
                           const int*   __restrict__ qtoks,
                           const float* __restrict__ fc_w,
                           const float* __restrict__ fc_b,
                           float*       __restrict__ out) {
    __shared__ float red[NK * NQ];
    __shared__ float ks[NK];
    int b = blockIdx.x;
    int t = threadIdx.x;
    if (t < NK * NQ) {
        int q = t & 15;
        float r = 0.f;
        for (int j = 0; j < BLOCKS_PER_B; ++j)
            r += part[(b * BLOCKS_PER_B + j) * (NK * NQ) + t];
        red[t] = (qtoks[b * NQ + q] != 0) ? logf(r + 1e-6f) : 0.f;
    }
    __syncthreads();
    if (t < NK) {
        float s = 0.f;
        for (int q = 0; q < NQ; ++q) s += red[t * NQ + q];
        ks[t] = s * fc_w[t];
    }
    __syncthreads();
    if (t == 0) {
        float s = fc_b[0];
        for (int k = 0; k < NK; ++k) s += ks[k];
        out[b] = s;
    }
}

extern "C" void kernel_launch(void* const* d_in, const int* in_sizes, int n_in,
                              void* d_out, int out_size, void* d_ws, size_t ws_size,
                              hipStream_t stream) {
    const int*   doctoks   = (const int*)  d_in[0];   // [128,1024]
    const int*   querytoks = (const int*)  d_in[1];   // [128,16]
    // d_in[2] = query_idf: unused by the reference
    const float* emb       = (const float*)d_in[3];   // [100000,300]
    const float* mus       = (const float*)d_in[4];   // [11]
    const float* sigmas    = (const float*)d_in[5];   // [11]
    const float* fc_w      = (const float*)d_in[6];   // [1,11]
    const float* fc_b      = (const float*)d_in[7];   // [1]
    float* out = (float*)d_out;                        // [128]

    float* part = (float*)d_ws;                        // [512][176] floats

    knrm_main<<<NB * BLOCKS_PER_B, BLOCK, 0, stream>>>(doctoks, querytoks, emb,
                                                       mus, sigmas, part);
    knrm_final<<<NB, 192, 0, stream>>>(part, querytoks, fc_w, fc_b, out);
}

// Round 4
// 212.281 us; speedup vs baseline: 1.0141x; 1.0141x over previous
//
#include <hip/hip_runtime.h>

#define EDIM 300
#define NB   128
#define NQ   16
#define ND   1024
#define NK   11
#define BLOCK 256                 // R12: 4 waves/block
#define MDOC  2                   // rows per lane (halved: doc range split across wave pairs)
#define TDOCS 256                 // docs per block
#define BLOCKS_PER_B 4            // 1024 / 256
#define NPANEL 10                 // 9 full 32-float panels + one 12-float remainder
#define PPITCH 36                 // panel row pitch in floats (32 + 4 pad)
#define SIMP 260                  // sim_t row pitch (256 + 4 pad)

// R12: occupancy restructure. R8-R11 post-mortem: 128-thr blocks = 2 waves; at
// 2 blocks/CU that is 1 wave/SIMD, and a block's waves are barrier-locked at the
// same phase -> when a wave drains its panel gather the SIMD has NOTHING else to
// issue. All intra-block pipelining attempts (R9-R11) were neutral; VALUBusy 33%
// == pure-compute/total, i.e. zero latency hiding. Fix: 256-thr blocks (4 waves),
// same ~76.6 KB LDS -> still 2 blocks/CU but now 2 waves/SIMD from two
// phase-INDEPENDENT blocks: block B computes while block A drains. Work split:
// wave = (q-half, doc-half), MDOC=2; staging 8 slices/thread; RBF uses 16
// doc-slices + in-wave shfl pair-reduce so red_s fits (2.8 KB).
#define BARRIER_LGKM() do { \
    asm volatile("s_waitcnt lgkmcnt(0)" ::: "memory"); \
    __builtin_amdgcn_s_barrier(); \
    asm volatile("" ::: "memory"); } while (0)

#define PF_L(j)  pf##j = *(const float4*)(rp##j + pp * 32)
#define PF_LOAD(p) do { const int pp = (p); if (pp < 9 || s < 3) { \
    PF_L(0); PF_L(1); PF_L(2); PF_L(3); PF_L(4); PF_L(5); PF_L(6); PF_L(7); } } while (0)

#define PF_S(j)  *(float4*)&panel[(r0 + 32 * (j)) * PPITCH + s * 4] = pf##j
#define PF_WRITE(p) do { if ((p) < 9 || s < 3) { \
    PF_S(0); PF_S(1); PF_S(2); PF_S(3); PF_S(4); PF_S(5); PF_S(6); PF_S(7); } } while (0)

__global__ __launch_bounds__(BLOCK, 1) void knrm_main(
    const int*   __restrict__ dtoks,
    const int*   __restrict__ qtoks,
    const float* __restrict__ emb,
    const float* __restrict__ mus,
    const float* __restrict__ sigmas,
    float*       __restrict__ part) {
    __shared__ __align__(16) float qn_s[NQ * EDIM];      // 19.2 KB
    __shared__ __align__(16) float panel[TDOCS * PPITCH];// 36.9 KB
    __shared__ int   dtok_s[TDOCS];                      // 1 KB
    __shared__ float rs_s[NQ];
    __shared__ __align__(16) float sim_t[NQ * SIMP];     // 16.6 KB
    __shared__ float red_s[NK * NQ * 4];                 // 2.8 KB
    // total ~76.6 KB -> 2 blocks/CU, 8 waves/CU, 2 waves/SIMD

    const int blk   = blockIdx.x;
    const int b     = blk >> 2;
    const int dbase = (blk & 3) * TDOCS;
    const int tid   = threadIdx.x;
    const int lane  = tid & 63;
    const int w     = tid >> 6;          // 0..3 (wave-uniform)
    const int qh    = w & 1;             // q-half
    const int dh    = w >> 1;            // doc-half

    // ---- doc-token tile + raw q rows (coalesced, float4-vectorized) ----
    for (int i = tid; i < TDOCS; i += BLOCK) dtok_s[i] = dtoks[b * ND + dbase + i];
    for (int i = tid; i < NQ * (EDIM / 4); i += BLOCK) {   // 300%4==0
        int q = i / (EDIM / 4), e4 = i - q * (EDIM / 4);
        ((float4*)qn_s)[i] =
            *(const float4*)(emb + (size_t)qtoks[b * NQ + q] * EDIM + e4 * 4);
    }
    __syncthreads();                     // dtok_s + raw qn_s visible

    const int s  = tid & 7;              // 128B slice index within a panel row
    const int r0 = tid >> 3;             // 0..31

    // hoisted per-thread row base pointers (rows fixed across panels)
    const float* rp0 = emb + (size_t)dtok_s[r0 +   0] * EDIM + s * 4;
    const float* rp1 = emb + (size_t)dtok_s[r0 +  32] * EDIM + s * 4;
    const float* rp2 = emb + (size_t)dtok_s[r0 +  64] * EDIM + s * 4;
    const float* rp3 = emb + (size_t)dtok_s[r0 +  96] * EDIM + s * 4;
    const float* rp4 = emb + (size_t)dtok_s[r0 + 128] * EDIM + s * 4;
    const float* rp5 = emb + (size_t)dtok_s[r0 + 160] * EDIM + s * 4;
    const float* rp6 = emb + (size_t)dtok_s[r0 + 192] * EDIM + s * 4;
    const float* rp7 = emb + (size_t)dtok_s[r0 + 224] * EDIM + s * 4;

    float4 pf0, pf1, pf2, pf3, pf4, pf5, pf6, pf7;   // 32 named VGPRs

    PF_LOAD(0);                          // panel-0 gather issued under q-norm phase
    {   // q norms: 16 lanes per q, 4 q's per wave
        int q = tid >> 4, j = tid & 15;
        float ss = 0.f;
        for (int e = j; e < EDIM; e += 16) { float v = qn_s[q * EDIM + e]; ss += v * v; }
        ss += __shfl_xor(ss, 1, 64);
        ss += __shfl_xor(ss, 2, 64);
        ss += __shfl_xor(ss, 4, 64);
        ss += __shfl_xor(ss, 8, 64);
        if (j == 0) rs_s[q] = 1.0f / (sqrtf(ss) + 1e-9f);
    }
    __syncthreads();
    for (int i = tid; i < NQ * (EDIM / 4); i += BLOCK) {
        float4 v = ((float4*)qn_s)[i];
        float r = rs_s[i / (EDIM / 4)];
        v.x *= r; v.y *= r; v.z *= r; v.w *= r;
        ((float4*)qn_s)[i] = v;
    }
    PF_WRITE(0);                         // panel 0 -> LDS (vmcnt wait lands here)
    PF_LOAD(1);                          // panel 1 issued
    BARRIER_LGKM();                      // panel 0 + scaled qn_s visible

    float sims[MDOC][8];
#pragma unroll
    for (int m = 0; m < MDOC; ++m)
#pragma unroll
        for (int qq = 0; qq < 8; ++qq) sims[m][qq] = 0.f;
    float ssq[MDOC] = {0.f, 0.f};

    const float* qbase = qn_s + (size_t)qh * 8 * EDIM;

    for (int p = 0; p < NPANEL; ++p) {
        // ---- compute on panel p (this wave's 128-doc half) ----
        const int cmax = (p == 9) ? 3 : 8;
        for (int cc = 0; cc < cmax; ++cc) {
            float4 dv[MDOC];
#pragma unroll
            for (int m = 0; m < MDOC; ++m)
                dv[m] = *(const float4*)&panel[(lane + 64 * (m + 2 * dh)) * PPITCH + cc * 4];
#pragma unroll
            for (int m = 0; m < MDOC; ++m)
                ssq[m] += dv[m].x*dv[m].x + dv[m].y*dv[m].y + dv[m].z*dv[m].z + dv[m].w*dv[m].w;
            const float* qb = qbase + (p * 8 + cc) * 4;
#pragma unroll
            for (int qq = 0; qq < 8; ++qq) {
                float4 qv = *(const float4*)(qb + qq * EDIM);   // LDS broadcast (wave-uniform)
#pragma unroll
                for (int m = 0; m < MDOC; ++m) {
                    sims[m][qq] += qv.x*dv[m].x + qv.y*dv[m].y + qv.z*dv[m].z + qv.w*dv[m].w;
                }
            }
        }
        BARRIER_LGKM();                  // panel p fully consumed
        if (p < 9) {
            PF_WRITE(p + 1);             // vmcnt wait lands here
            if (p < 8) PF_LOAD(p + 2);   // next gather issued
            BARRIER_LGKM();              // panel p+1 ready
        }
    }

    // ---- normalize + write sim_t (pad docs: tok0 -> zero row -> sim 0) ----
#pragma unroll
    for (int m = 0; m < MDOC; ++m) {
        float rn = 1.0f / (sqrtf(ssq[m]) + 1e-9f);
#pragma unroll
        for (int qq = 0; qq < 8; ++qq)
            sim_t[(qh * 8 + qq) * SIMP + lane + 64 * m + 128 * dh] = sims[m][qq] * rn;
    }
    __syncthreads();

    // ---- RBF bank: thread = (q = tid&15, slice sl of 16 x 16 docs) ----
    {
        const int q  = tid & 15;
        const int sl = tid >> 4;         // 0..15
        float mu[NK], cc2[NK], acc[NK];
#pragma unroll
        for (int k = 0; k < NK; ++k) {
            mu[k] = mus[k];
            float sg = sigmas[k];
            cc2[k] = -0.5f / (sg * sg);
            acc[k] = 0.f;
        }
        const float* row = sim_t + q * SIMP + sl * 16;
#pragma unroll
        for (int i = 0; i < 4; ++i) {
            float4 s4 = *(const float4*)(row + i * 4);
#pragma unroll
            for (int k = 0; k < NK; ++k) {
                float e0 = s4.x - mu[k], e1 = s4.y - mu[k];
                float e2 = s4.z - mu[k], e3 = s4.w - mu[k];
                acc[k] += __expf(cc2[k]*e0*e0) + __expf(cc2[k]*e1*e1)
                        + __expf(cc2[k]*e2*e2) + __expf(cc2[k]*e3*e3);
            }
        }
        // pair-reduce sl bit0 (tid^16) and bit1 (tid^32) — both in-wave
#pragma unroll
        for (int k = 0; k < NK; ++k) {
            acc[k] += __shfl_xor(acc[k], 16, 64);
            acc[k] += __shfl_xor(acc[k], 32, 64);
        }
        if ((sl & 3) == 0) {
#pragma unroll
            for (int k = 0; k < NK; ++k)
                red_s[(k * NQ + q) * 4 + (sl >> 2)] = acc[k];
        }
    }
    __syncthreads();

    // 176 outputs, 256 threads: single strided pass
    for (int t = tid; t < NK * NQ; t += BLOCK) {
        float r = red_s[t * 4] + red_s[t * 4 + 1] + red_s[t * 4 + 2] + red_s[t * 4 + 3];
        part[blk * (NK * NQ) + t] = r;
    }
}

// ---------------- Kernel 2: sum partials, masked log-sum over q, FC ----------------
__global__ void knrm_final(const float* __restrict__ part,
                           const int*   __restrict__ qtoks,
                           const float* __restrict__ fc_w,
                           const float* __restrict__ fc_b,
                           float*       __restrict__ out) {
    __shared__ float red[NK * NQ];
    __shared__ float ks[NK];
    int b = blockIdx.x;
    int t = threadIdx.x;
    if (t < NK * NQ) {
        int q = t & 15;
        float r = 0.f;
        for (int j = 0; j < BLOCKS_PER_B; ++j)
            r += part[(b * BLOCKS_PER_B + j) * (NK * NQ) + t];
        red[t] = (qtoks[b * NQ + q] != 0) ? logf(r + 1e-6f) : 0.f;
    }
    __syncthreads();
    if (t < NK) {
        float s = 0.f;
        for (int q = 0; q < NQ; ++q) s += red[t * NQ + q];
        ks[t] = s * fc_w[t];
    }
    __syncthreads();
    if (t == 0) {
        float s = fc_b[0];
        for (int k = 0; k < NK; ++k) s += ks[k];
        out[b] = s;
    }
}

extern "C" void kernel_launch(void* const* d_in, const int* in_sizes, int n_in,
                              void* d_out, int out_size, void* d_ws, size_t ws_size,
                              hipStream_t stream) {
    const int*   doctoks   = (const int*)  d_in[0];   // [128,1024]
    const int*   querytoks = (const int*)  d_in[1];   // [128,16]
    // d_in[2] = query_idf: unused by the reference
    const float* emb       = (const float*)d_in[3];   // [100000,300]
    const float* mus       = (const float*)d_in[4];   // [11]
    const float* sigmas    = (const float*)d_in[5];   // [11]
    const float* fc_w      = (const float*)d_in[6];   // [1,11]
    const float* fc_b      = (const float*)d_in[7];   // [1]
    float* out = (float*)d_out;                        // [128]

    float* part = (float*)d_ws;                        // [512][176] floats

    knrm_main<<<NB * BLOCKS_PER_B, BLOCK, 0, stream>>>(doctoks, querytoks, emb,
                                                       mus, sigmas, part);
    knrm_final<<<NB, 192, 0, stream>>>(part, querytoks, fc_w, fc_b, out);
}